// Round 4
// baseline (8614.709 us; speedup 1.0000x reference)
//
#include <hip/hip_runtime.h>
#include <math.h>

#define BN 4
#define NN 4096
#define MM 16384   // BN*NN
#define DD 128
#define KK 8
#define NBLK 12

// ---------------- init: h[(b*N+n), k] = feat[b, k, n] ----------------------
__global__ void k_init_h(const float* __restrict__ feat, float* __restrict__ h) {
    __shared__ float tile[64][65];
    int b = blockIdx.y;
    int n0 = blockIdx.x * 64;
    int t = threadIdx.x;
    int lane = t & 63, grp = t >> 6;
    for (int kp = 0; kp < 2; ++kp) {
        int k0 = kp * 64;
        for (int r = grp; r < 64; r += 4)
            tile[r][lane] = feat[((size_t)(b * DD + k0 + r)) * NN + n0 + lane];
        __syncthreads();
        for (int r = grp; r < 64; r += 4)
            h[(size_t)(b * NN + n0 + r) * DD + k0 + lane] = tile[lane][r];
        __syncthreads();
    }
}

// ---------------- sq[m] = sum_k h[m,k]^2 ----------------------------------
__global__ void k_sq(const float* __restrict__ h, float* __restrict__ sq) {
    int m = blockIdx.x * 4 + (threadIdx.x >> 6);
    int lane = threadIdx.x & 63;
    const float2* hp = (const float2*)(h + (size_t)m * DD);
    float2 v = hp[lane];
    float s = v.x * v.x + v.y * v.y;
    #pragma unroll
    for (int o = 32; o; o >>= 1) s += __shfl_xor(s, o);
    if (lane == 0) sq[m] = s;
}

// ---------------- kNN: per batch, top-8 smallest (sqq + sqc - 2*dot) ------
__global__ __launch_bounds__(256) void k_knn(const float* __restrict__ h,
                                             const float* __restrict__ sq,
                                             int* __restrict__ idx) {
    __shared__ float sQ[128 * 64];   // k-major [k][m]
    __shared__ float sC[128 * 64];   // k-major [k][c]
    __shared__ float sSq[64];
    __shared__ float sQq[64];
    int b = blockIdx.y;
    int q0 = blockIdx.x * 64;
    int t = threadIdx.x;
    int tx = t & 15, ty = t >> 4;
    const float* hb = h + (size_t)b * NN * DD;

    {
        const float4* hq4 = (const float4*)(hb + (size_t)q0 * DD);
        for (int e = t; e < 64 * 32; e += 256) {
            int row = e >> 5, c4 = e & 31;
            float4 v = hq4[row * 32 + c4];
            sQ[(c4 * 4 + 0) * 64 + row] = v.x;
            sQ[(c4 * 4 + 1) * 64 + row] = v.y;
            sQ[(c4 * 4 + 2) * 64 + row] = v.z;
            sQ[(c4 * 4 + 3) * 64 + row] = v.w;
        }
        if (t < 64) sQq[t] = sq[b * NN + q0 + t];
    }

    float d8[4][8];
    int   id8[4][8];
    float wv[4];
    int   wsl[4];
    #pragma unroll
    for (int i = 0; i < 4; i++) {
        wv[i] = 1e30f; wsl[i] = 0;
        #pragma unroll
        for (int s = 0; s < 8; s++) { d8[i][s] = 1e30f; id8[i][s] = 0; }
    }

    for (int c0 = 0; c0 < NN; c0 += 64) {
        __syncthreads();
        const float4* hc4 = (const float4*)(hb + (size_t)c0 * DD);
        for (int e = t; e < 64 * 32; e += 256) {
            int row = e >> 5, c4 = e & 31;
            float4 v = hc4[row * 32 + c4];
            sC[(c4 * 4 + 0) * 64 + row] = v.x;
            sC[(c4 * 4 + 1) * 64 + row] = v.y;
            sC[(c4 * 4 + 2) * 64 + row] = v.z;
            sC[(c4 * 4 + 3) * 64 + row] = v.w;
        }
        if (t < 64) sSq[t] = sq[b * NN + c0 + t];
        __syncthreads();

        float acc[4][4];
        #pragma unroll
        for (int i = 0; i < 4; i++)
            #pragma unroll
            for (int j = 0; j < 4; j++) acc[i][j] = 0.f;

        const float4* Q4 = (const float4*)sQ;
        const float4* C4 = (const float4*)sC;
        #pragma unroll 8
        for (int k = 0; k < 128; ++k) {
            float4 a = Q4[k * 16 + ty];
            float4 c = C4[k * 16 + tx];
            float av[4] = {a.x, a.y, a.z, a.w};
            float cv[4] = {c.x, c.y, c.z, c.w};
            #pragma unroll
            for (int i = 0; i < 4; i++)
                #pragma unroll
                for (int j = 0; j < 4; j++) acc[i][j] += av[i] * cv[j];
        }

        // keys like the reference: (sq_q + sq_c) - 2*dot ; self excluded
        #pragma unroll
        for (int j = 0; j < 4; j++) {
            int cl = c0 + tx * 4 + j;
            float sc = sSq[tx * 4 + j];
            #pragma unroll
            for (int i = 0; i < 4; i++) {
                int ql = q0 + ty * 4 + i;
                float key = (sQq[ty * 4 + i] + sc) - 2.f * acc[i][j];
                if (cl != ql && key < wv[i]) {
                    #pragma unroll
                    for (int s = 0; s < 8; s++)
                        if (s == wsl[i]) { d8[i][s] = key; id8[i][s] = cl; }
                    float w = d8[i][0]; int sl = 0;
                    #pragma unroll
                    for (int s = 1; s < 8; s++)
                        if (d8[i][s] > w) { w = d8[i][s]; sl = s; }
                    wv[i] = w; wsl[i] = sl;
                }
            }
        }
    }

    // merge 16 partial top-8s per query via LDS (ascending candidate order
    // within each tx-list; tx ascending => top_k lowest-index tie behavior)
    __syncthreads();
    int* sCi = (int*)sC;
    #pragma unroll
    for (int i = 0; i < 4; i++) {
        int q = ty * 4 + i;
        #pragma unroll
        for (int s = 0; s < 8; s++) {
            sQ[q * 128 + tx * 8 + s] = d8[i][s];
            sCi[q * 128 + tx * 8 + s] = id8[i][s];
        }
    }
    __syncthreads();
    if (t < 64) {
        int q = t;
        float bd[8]; int bi[8]; float w = 1e30f; int sl = 0;
        #pragma unroll
        for (int s = 0; s < 8; s++) { bd[s] = 1e30f; bi[s] = 0; }
        for (int e = 0; e < 128; ++e) {
            float key = sQ[q * 128 + e];
            int cd = sCi[q * 128 + e];
            if (key < w) {
                #pragma unroll
                for (int s = 0; s < 8; s++)
                    if (s == sl) { bd[s] = key; bi[s] = cd; }
                w = bd[0]; sl = 0;
                #pragma unroll
                for (int s = 1; s < 8; s++)
                    if (bd[s] > w) { w = bd[s]; sl = s; }
            }
        }
        int* op = idx + (size_t)(b * NN + q0 + q) * KK;
        #pragma unroll
        for (int s = 0; s < 8; s++) op[s] = b * NN + bi[s];
    }
}

// ------- fused GCN: agg-first + GEMM.  mode 0: R = relu(agg(S)@W + b)
//                                       mode 1: R = R + agg(S)@W + b
__global__ __launch_bounds__(256) void k_gcn(const float* __restrict__ S,
                                             const int* __restrict__ idx,
                                             const float* __restrict__ W,
                                             const float* __restrict__ bias,
                                             float* __restrict__ R,
                                             int mode) {
    __shared__ float sW[128 * 128];  // [k][n] 64KB
    __shared__ float sA[128 * 64];   // [k][m] 32KB
    int t = threadIdx.x;
    int m0 = blockIdx.x * 64;

    {
        int row = t >> 2, quad = t & 3;
        size_t gm = m0 + row;
        const float4* S4 = (const float4*)S;
        const int* ip = idx + gm * KK;
        int nb[8];
        #pragma unroll
        for (int j = 0; j < 8; j++) nb[j] = ip[j];
        float4 a[8];
        #pragma unroll
        for (int j = 0; j < 8; j++) a[j] = S4[gm * 32 + quad * 8 + j];
        for (int e = 0; e < 8; e++) {
            const float4* p = S4 + (size_t)nb[e] * 32 + quad * 8;
            #pragma unroll
            for (int j = 0; j < 8; j++) {
                float4 v = p[j];
                a[j].x += v.x; a[j].y += v.y; a[j].z += v.z; a[j].w += v.w;
            }
        }
        const float ninth = 1.f / 9.f;
        #pragma unroll
        for (int j = 0; j < 8; j++) {
            int k = quad * 32 + j * 4;
            sA[(k + 0) * 64 + row] = a[j].x * ninth;
            sA[(k + 1) * 64 + row] = a[j].y * ninth;
            sA[(k + 2) * 64 + row] = a[j].z * ninth;
            sA[(k + 3) * 64 + row] = a[j].w * ninth;
        }
    }
    {
        const float4* w4 = (const float4*)W;
        float4* sW4w = (float4*)sW;
        for (int e = t; e < 4096; e += 256) sW4w[e] = w4[e];
    }
    __syncthreads();

    int tx = t & 15, ty = t >> 4;
    float acc[4][8];
    #pragma unroll
    for (int i = 0; i < 4; i++)
        #pragma unroll
        for (int j = 0; j < 8; j++) acc[i][j] = 0.f;

    const float4* sA4 = (const float4*)sA;
    const float4* sW4 = (const float4*)sW;
    #pragma unroll 4
    for (int k = 0; k < 128; ++k) {
        float4 a = sA4[k * 16 + ty];
        float4 w0 = sW4[k * 32 + tx * 2 + 0];
        float4 w1 = sW4[k * 32 + tx * 2 + 1];
        float av[4] = {a.x, a.y, a.z, a.w};
        float wv[8] = {w0.x, w0.y, w0.z, w0.w, w1.x, w1.y, w1.z, w1.w};
        #pragma unroll
        for (int i = 0; i < 4; i++)
            #pragma unroll
            for (int j = 0; j < 8; j++) acc[i][j] += av[i] * wv[j];
    }

    float bia[8];
    #pragma unroll
    for (int j = 0; j < 8; j++) bia[j] = bias[tx * 8 + j];

    #pragma unroll
    for (int i = 0; i < 4; i++) {
        size_t m = m0 + ty * 4 + i;
        float4* rp = (float4*)(R + m * DD + tx * 8);
        float v[8];
        #pragma unroll
        for (int j = 0; j < 8; j++) v[j] = acc[i][j] + bia[j];
        if (mode == 0) {
            #pragma unroll
            for (int j = 0; j < 8; j++) v[j] = fmaxf(v[j], 0.f);
        } else {
            float4 r0 = rp[0], r1 = rp[1];
            v[0] += r0.x; v[1] += r0.y; v[2] += r0.z; v[3] += r0.w;
            v[4] += r1.x; v[5] += r1.y; v[6] += r1.z; v[7] += r1.w;
        }
        rp[0] = make_float4(v[0], v[1], v[2], v[3]);
        rp[1] = make_float4(v[4], v[5], v[6], v[7]);
    }
}

// ---------------- plain GEMM (final h @ Wp1) ------------------------------
__global__ __launch_bounds__(256) void k_gemm(const float* __restrict__ A,
                                              const float* __restrict__ W,
                                              float* __restrict__ C) {
    __shared__ float sW[128 * 128];
    __shared__ float sA[128 * 64];
    int t = threadIdx.x;
    int m0 = blockIdx.x * 64;

    const float4* w4 = (const float4*)W;
    float4* sW4w = (float4*)sW;
    for (int e = t; e < 4096; e += 256) sW4w[e] = w4[e];

    const float4* A4 = (const float4*)(A + (size_t)m0 * DD);
    for (int e = t; e < 64 * 32; e += 256) {
        int row = e >> 5, c4 = e & 31;
        float4 v = A4[row * 32 + c4];
        sA[(c4 * 4 + 0) * 64 + row] = v.x;
        sA[(c4 * 4 + 1) * 64 + row] = v.y;
        sA[(c4 * 4 + 2) * 64 + row] = v.z;
        sA[(c4 * 4 + 3) * 64 + row] = v.w;
    }
    __syncthreads();

    int tx = t & 15, ty = t >> 4;
    float acc[4][8];
    #pragma unroll
    for (int i = 0; i < 4; i++)
        #pragma unroll
        for (int j = 0; j < 8; j++) acc[i][j] = 0.f;

    const float4* sA4 = (const float4*)sA;
    const float4* sW4 = (const float4*)sW;
    #pragma unroll 4
    for (int k = 0; k < 128; ++k) {
        float4 a = sA4[k * 16 + ty];
        float4 w0 = sW4[k * 32 + tx * 2 + 0];
        float4 w1 = sW4[k * 32 + tx * 2 + 1];
        float av[4] = {a.x, a.y, a.z, a.w};
        float wv[8] = {w0.x, w0.y, w0.z, w0.w, w1.x, w1.y, w1.z, w1.w};
        #pragma unroll
        for (int i = 0; i < 4; i++)
            #pragma unroll
            for (int j = 0; j < 8; j++) acc[i][j] += av[i] * wv[j];
    }
    #pragma unroll
    for (int i = 0; i < 4; i++) {
        float4* cp = (float4*)(C + (size_t)(m0 + ty * 4 + i) * DD + tx * 8);
        cp[0] = make_float4(acc[i][0], acc[i][1], acc[i][2], acc[i][3]);
        cp[1] = make_float4(acc[i][4], acc[i][5], acc[i][6], acc[i][7]);
    }
}

// ---------------- final: LN -> ReLU -> Wp2 -> tanh*0.1 -> new_xyz (f32) ---
__global__ void k_final(const float* __restrict__ Z, const float* __restrict__ bp1,
                        const float* __restrict__ lng, const float* __restrict__ lnb,
                        const float* __restrict__ Wp2, const float* __restrict__ bp2,
                        const float* __restrict__ xyz, float* __restrict__ out0) {
    int m = blockIdx.x * 4 + (threadIdx.x >> 6);
    int lane = threadIdx.x & 63;
    int b = m >> 12, n = m & 4095;
    const float2* zp = (const float2*)(Z + (size_t)m * DD);
    float2 z = zp[lane];
    float z0 = z.x + bp1[lane * 2];
    float z1 = z.y + bp1[lane * 2 + 1];
    float s = z0 + z1;
    #pragma unroll
    for (int o = 32; o; o >>= 1) s += __shfl_xor(s, o);
    float mu = s * (1.f / 128.f);
    float d0 = z0 - mu, d1 = z1 - mu;
    float v = d0 * d0 + d1 * d1;
    #pragma unroll
    for (int o = 32; o; o >>= 1) v += __shfl_xor(v, o);
    float rstd = rsqrtf(v * (1.f / 128.f) + 1e-5f);
    float r0 = d0 * rstd * lng[lane * 2] + lnb[lane * 2];
    float r1 = d1 * rstd * lng[lane * 2 + 1] + lnb[lane * 2 + 1];
    r0 = fmaxf(r0, 0.f); r1 = fmaxf(r1, 0.f);
    float off[6];
    #pragma unroll
    for (int o = 0; o < 6; o++) {
        float p = r0 * Wp2[(lane * 2) * 6 + o] + r1 * Wp2[(lane * 2 + 1) * 6 + o];
        #pragma unroll
        for (int x = 32; x; x >>= 1) p += __shfl_xor(p, x);
        off[o] = p;
    }
    if (lane == 0) {
        #pragma unroll
        for (int c = 0; c < 3; c++) {
            float base = xyz[((size_t)b * 3 + c) * NN + n];
            #pragma unroll
            for (int u = 0; u < 2; u++) {
                float val = tanhf(off[c * 2 + u] + bp2[c * 2 + u]) * 0.1f;
                out0[((size_t)b * 3 + c) * (2 * NN) + u * NN + n] = base + val;
            }
        }
    }
}

// ---------------- new_feat[b,k,n] = h[(b*N+n),k]  (f32) -------------------
__global__ void k_feat_out(const float* __restrict__ h, float* __restrict__ out1) {
    __shared__ float tile[64][65];
    int b = blockIdx.z, kp = blockIdx.y;
    int n0 = blockIdx.x * 64;
    int t = threadIdx.x;
    int lane = t & 63, grp = t >> 6;
    int k0 = kp * 64;
    for (int r = grp; r < 64; r += 4)
        tile[r][lane] = h[(size_t)(b * NN + n0 + r) * DD + k0 + lane];
    __syncthreads();
    for (int r = grp; r < 64; r += 4)
        out1[((size_t)(b * DD + k0 + r)) * NN + n0 + lane] = tile[lane][r];
}

extern "C" void kernel_launch(void* const* d_in, const int* in_sizes, int n_in,
                              void* d_out, int out_size, void* d_ws, size_t ws_size,
                              hipStream_t stream) {
    const float* xyz  = (const float*)d_in[0];
    const float* feat = (const float*)d_in[1];
    const float* Wa   = (const float*)d_in[2];
    const float* ba   = (const float*)d_in[3];
    const float* Wb   = (const float*)d_in[4];
    const float* bb   = (const float*)d_in[5];
    const float* Wp1  = (const float*)d_in[6];
    const float* bp1  = (const float*)d_in[7];
    const float* lng  = (const float*)d_in[8];
    const float* lnb  = (const float*)d_in[9];
    const float* Wp2  = (const float*)d_in[10];
    const float* bp2  = (const float*)d_in[11];

    float* h   = (float*)d_ws;                 // 8 MB
    float* X   = h + (size_t)MM * DD;          // 8 MB
    float* sq  = X + (size_t)MM * DD;          // 64 KB
    int*   idx = (int*)(sq + MM);              // 512 KB   (total 16.56 MB)

    float* out0 = (float*)d_out;                          // (B,3,2N)
    float* out1 = out0 + (size_t)BN * 3 * 2 * NN;         // (B,DIM,N)

    k_init_h<<<dim3(NN / 64, BN), 256, 0, stream>>>(feat, h);

    for (int i = 0; i < NBLK; i++) {
        k_sq<<<MM / 4, 256, 0, stream>>>(h, sq);
        k_knn<<<dim3(NN / 64, BN), 256, 0, stream>>>(h, sq, idx);
        k_gcn<<<MM / 64, 256, 0, stream>>>(h, idx, Wa + (size_t)i * DD * DD, ba + i * DD, X, 0);
        k_gcn<<<MM / 64, 256, 0, stream>>>(X, idx, Wb + (size_t)i * DD * DD, bb + i * DD, h, 1);
    }

    k_gemm<<<MM / 64, 256, 0, stream>>>(h, Wp1, X);
    k_final<<<MM / 4, 256, 0, stream>>>(X, bp1, lng, lnb, Wp2, bp2, xyz, out0);
    k_feat_out<<<dim3(NN / 64, 2, BN), 256, 0, stream>>>(h, out1);
}

// Round 9
// 7919.298 us; speedup vs baseline: 1.0878x; 1.0878x over previous
//
#include <hip/hip_runtime.h>
#include <math.h>

#define BN 4
#define NN 4096
#define MM 16384   // BN*NN
#define DD 128
#define KK 8
#define NBLK 12

// ---------------- init: h[(b*N+n), k] = feat[b, k, n] ----------------------
__global__ void k_init_h(const float* __restrict__ feat, float* __restrict__ h) {
    __shared__ float tile[64][65];
    int b = blockIdx.y;
    int n0 = blockIdx.x * 64;
    int t = threadIdx.x;
    int lane = t & 63, grp = t >> 6;
    for (int kp = 0; kp < 2; ++kp) {
        int k0 = kp * 64;
        for (int r = grp; r < 64; r += 4)
            tile[r][lane] = feat[((size_t)(b * DD + k0 + r)) * NN + n0 + lane];
        __syncthreads();
        for (int r = grp; r < 64; r += 4)
            h[(size_t)(b * NN + n0 + r) * DD + k0 + lane] = tile[lane][r];
        __syncthreads();
    }
}

// ---------------- sq[m] = sum_k h[m,k]^2 ----------------------------------
__global__ void k_sq(const float* __restrict__ h, float* __restrict__ sq) {
    int m = blockIdx.x * 4 + (threadIdx.x >> 6);
    int lane = threadIdx.x & 63;
    const float2* hp = (const float2*)(h + (size_t)m * DD);
    float2 v = hp[lane];
    float s = v.x * v.x + v.y * v.y;
    #pragma unroll
    for (int o = 32; o; o >>= 1) s += __shfl_xor(s, o);
    if (lane == 0) sq[m] = s;
}

// ---- inline-asm FMA: pins one IEEE fma per call, opaque to the optimizer --
__device__ __forceinline__ float fma_asm(float a, float b, float c) {
    float d;
    asm("v_fma_f32 %0, %1, %2, %3" : "=v"(d) : "v"(a), "v"(b), "v"(c));
    return d;
}

// ---------------- kNN v6: round-4 arithmetic, conflict-free memory --------
// grid (NN/64, BN), block 256. Thread (tx,ty) owns queries ty*4+i and
// candidates tx+16j of each 64-candidate tile. Dot chains are inline-asm
// v_fma_f32, strictly ascending k per accumulator (round-4 scheme, locked).
// Tiles row-major padded (33 float4 stride): b128 staging conflict-free,
// candidate reads 2-way (free), query reads broadcast. Merge verbatim r4.
__global__ __launch_bounds__(256) void k_knn(const float* __restrict__ h,
                                             const float* __restrict__ sq,
                                             int* __restrict__ idx) {
    __shared__ float sQ[64 * 132];
    __shared__ float sC[64 * 132];
    __shared__ float sSq[64];
    __shared__ float sQq[64];
    int b = blockIdx.y;
    int q0 = blockIdx.x * 64;
    int t = threadIdx.x;
    int tx = t & 15, ty = t >> 4;
    const float* hb = h + (size_t)b * NN * DD;

    float4* sQ4w = (float4*)sQ;
    float4* sC4w = (float4*)sC;
    const float4* sQ4 = (const float4*)sQ;
    const float4* sC4 = (const float4*)sC;

    // stage Q tile row-major
    {
        const float4* src = (const float4*)(hb + (size_t)q0 * DD);
        #pragma unroll
        for (int i2 = 0; i2 < 8; i2++) {
            int e = t + i2 * 256;
            int row = e >> 5, k4 = e & 31;
            sQ4w[row * 33 + k4] = src[row * 32 + k4];
        }
        if (t < 64) sQq[t] = sq[b * NN + q0 + t];
    }

    float d8[4][8];
    int   id8[4][8];
    float wv[4];
    int   wsl[4];
    #pragma unroll
    for (int i = 0; i < 4; i++) {
        wv[i] = 1e30f; wsl[i] = 0;
        #pragma unroll
        for (int s = 0; s < 8; s++) { d8[i][s] = 1e30f; id8[i][s] = 0; }
    }

    for (int c0 = 0; c0 < NN; c0 += 64) {
        __syncthreads();
        {
            const float4* src = (const float4*)(hb + (size_t)c0 * DD);
            #pragma unroll
            for (int i2 = 0; i2 < 8; i2++) {
                int e = t + i2 * 256;
                int row = e >> 5, k4 = e & 31;
                sC4w[row * 33 + k4] = src[row * 32 + k4];
            }
            if (t < 64) sSq[t] = sq[b * NN + c0 + t];
        }
        __syncthreads();

        float acc[4][4];
        #pragma unroll
        for (int i = 0; i < 4; i++)
            #pragma unroll
            for (int j = 0; j < 4; j++) acc[i][j] = 0.f;

        // asm-locked chains: acc[i][j] accumulates k=0..127 strictly ascending
        #pragma unroll 2
        for (int kq = 0; kq < 32; ++kq) {
            float4 qa[4], ca[4];
            #pragma unroll
            for (int i = 0; i < 4; i++) qa[i] = sQ4[(ty * 4 + i) * 33 + kq];
            #pragma unroll
            for (int j = 0; j < 4; j++) ca[j] = sC4[(tx + 16 * j) * 33 + kq];
            #pragma unroll
            for (int i = 0; i < 4; i++)
                #pragma unroll
                for (int j = 0; j < 4; j++) {
                    acc[i][j] = fma_asm(qa[i].x, ca[j].x, acc[i][j]);
                    acc[i][j] = fma_asm(qa[i].y, ca[j].y, acc[i][j]);
                    acc[i][j] = fma_asm(qa[i].z, ca[j].z, acc[i][j]);
                    acc[i][j] = fma_asm(qa[i].w, ca[j].w, acc[i][j]);
                }
        }

        // epilogue: round-4 text; candidate id/scale adjusted to partition
        #pragma unroll
        for (int j = 0; j < 4; j++) {
            int cl = c0 + tx + 16 * j;
            float sc = sSq[tx + 16 * j];
            #pragma unroll
            for (int i = 0; i < 4; i++) {
                int ql = q0 + ty * 4 + i;
                float key = (sQq[ty * 4 + i] + sc) - 2.f * acc[i][j];
                if (cl != ql && key < wv[i]) {
                    #pragma unroll
                    for (int s = 0; s < 8; s++)
                        if (s == wsl[i]) { d8[i][s] = key; id8[i][s] = cl; }
                    float w = d8[i][0]; int sl = 0;
                    #pragma unroll
                    for (int s = 1; s < 8; s++)
                        if (d8[i][s] > w) { w = d8[i][s]; sl = s; }
                    wv[i] = w; wsl[i] = sl;
                }
            }
        }
    }

    // merge 16 partial top-8s per query via LDS — verbatim round 4
    __syncthreads();
    int* sCi = (int*)sC;
    #pragma unroll
    for (int i = 0; i < 4; i++) {
        int q = ty * 4 + i;
        #pragma unroll
        for (int s = 0; s < 8; s++) {
            sQ[q * 128 + tx * 8 + s] = d8[i][s];
            sCi[q * 128 + tx * 8 + s] = id8[i][s];
        }
    }
    __syncthreads();
    if (t < 64) {
        int q = t;
        float bd[8]; int bi[8]; float w = 1e30f; int sl = 0;
        #pragma unroll
        for (int s = 0; s < 8; s++) { bd[s] = 1e30f; bi[s] = 0; }
        for (int e = 0; e < 128; ++e) {
            int e2 = (e & 96) | ((e & 31) ^ (q & 31));
            float key = sQ[q * 128 + e2];
            int cd = sCi[q * 128 + e2];
            if (key < w) {
                #pragma unroll
                for (int s = 0; s < 8; s++)
                    if (s == sl) { bd[s] = key; bi[s] = cd; }
                w = bd[0]; sl = 0;
                #pragma unroll
                for (int s = 1; s < 8; s++)
                    if (bd[s] > w) { w = bd[s]; sl = s; }
            }
        }
        int* op = idx + (size_t)(b * NN + q0 + q) * KK;
        #pragma unroll
        for (int s = 0; s < 8; s++) op[s] = b * NN + bi[s];
    }
}

// ------- fused GCN: agg-first + GEMM.  mode 0: R = relu(agg(S)@W + b)
//                                       mode 1: R = R + agg(S)@W + b
__global__ __launch_bounds__(256) void k_gcn(const float* __restrict__ S,
                                             const int* __restrict__ idx,
                                             const float* __restrict__ W,
                                             const float* __restrict__ bias,
                                             float* __restrict__ R,
                                             int mode) {
    __shared__ float sW[128 * 128];  // [k][n] 64KB
    __shared__ float sA[128 * 64];   // [k][m] 32KB
    int t = threadIdx.x;
    int m0 = blockIdx.x * 64;

    {
        int row = t >> 2, quad = t & 3;
        size_t gm = m0 + row;
        const float4* S4 = (const float4*)S;
        const int* ip = idx + gm * KK;
        int nb[8];
        #pragma unroll
        for (int j = 0; j < 8; j++) nb[j] = ip[j];
        float4 a[8];
        #pragma unroll
        for (int j = 0; j < 8; j++) a[j] = S4[gm * 32 + quad * 8 + j];
        for (int e = 0; e < 8; e++) {
            const float4* p = S4 + (size_t)nb[e] * 32 + quad * 8;
            #pragma unroll
            for (int j = 0; j < 8; j++) {
                float4 v = p[j];
                a[j].x += v.x; a[j].y += v.y; a[j].z += v.z; a[j].w += v.w;
            }
        }
        const float ninth = 1.f / 9.f;
        #pragma unroll
        for (int j = 0; j < 8; j++) {
            int k = quad * 32 + j * 4;
            sA[(k + 0) * 64 + row] = a[j].x * ninth;
            sA[(k + 1) * 64 + row] = a[j].y * ninth;
            sA[(k + 2) * 64 + row] = a[j].z * ninth;
            sA[(k + 3) * 64 + row] = a[j].w * ninth;
        }
    }
    {
        const float4* w4 = (const float4*)W;
        float4* sW4w = (float4*)sW;
        for (int e = t; e < 4096; e += 256) sW4w[e] = w4[e];
    }
    __syncthreads();

    int tx = t & 15, ty = t >> 4;
    float acc[4][8];
    #pragma unroll
    for (int i = 0; i < 4; i++)
        #pragma unroll
        for (int j = 0; j < 8; j++) acc[i][j] = 0.f;

    const float4* sA4 = (const float4*)sA;
    const float4* sW4 = (const float4*)sW;
    #pragma unroll 4
    for (int k = 0; k < 128; ++k) {
        float4 a = sA4[k * 16 + ty];
        float4 w0 = sW4[k * 32 + tx * 2 + 0];
        float4 w1 = sW4[k * 32 + tx * 2 + 1];
        float av[4] = {a.x, a.y, a.z, a.w};
        float wv[8] = {w0.x, w0.y, w0.z, w0.w, w1.x, w1.y, w1.z, w1.w};
        #pragma unroll
        for (int i = 0; i < 4; i++)
            #pragma unroll
            for (int j = 0; j < 8; j++) acc[i][j] += av[i] * wv[j];
    }

    float bia[8];
    #pragma unroll
    for (int j = 0; j < 8; j++) bia[j] = bias[tx * 8 + j];

    #pragma unroll
    for (int i = 0; i < 4; i++) {
        size_t m = m0 + ty * 4 + i;
        float4* rp = (float4*)(R + m * DD + tx * 8);
        float v[8];
        #pragma unroll
        for (int j = 0; j < 8; j++) v[j] = acc[i][j] + bia[j];
        if (mode == 0) {
            #pragma unroll
            for (int j = 0; j < 8; j++) v[j] = fmaxf(v[j], 0.f);
        } else {
            float4 r0 = rp[0], r1 = rp[1];
            v[0] += r0.x; v[1] += r0.y; v[2] += r0.z; v[3] += r0.w;
            v[4] += r1.x; v[5] += r1.y; v[6] += r1.z; v[7] += r1.w;
        }
        rp[0] = make_float4(v[0], v[1], v[2], v[3]);
        rp[1] = make_float4(v[4], v[5], v[6], v[7]);
    }
}

// ---------------- plain GEMM (final h @ Wp1) ------------------------------
__global__ __launch_bounds__(256) void k_gemm(const float* __restrict__ A,
                                              const float* __restrict__ W,
                                              float* __restrict__ C) {
    __shared__ float sW[128 * 128];
    __shared__ float sA[128 * 64];
    int t = threadIdx.x;
    int m0 = blockIdx.x * 64;

    const float4* w4 = (const float4*)W;
    float4* sW4w = (float4*)sW;
    for (int e = t; e < 4096; e += 256) sW4w[e] = w4[e];

    const float4* A4 = (const float4*)(A + (size_t)m0 * DD);
    for (int e = t; e < 64 * 32; e += 256) {
        int row = e >> 5, c4 = e & 31;
        float4 v = A4[row * 32 + c4];
        sA[(c4 * 4 + 0) * 64 + row] = v.x;
        sA[(c4 * 4 + 1) * 64 + row] = v.y;
        sA[(c4 * 4 + 2) * 64 + row] = v.z;
        sA[(c4 * 4 + 3) * 64 + row] = v.w;
    }
    __syncthreads();

    int tx = t & 15, ty = t >> 4;
    float acc[4][8];
    #pragma unroll
    for (int i = 0; i < 4; i++)
        #pragma unroll
        for (int j = 0; j < 8; j++) acc[i][j] = 0.f;

    const float4* sA4 = (const float4*)sA;
    const float4* sW4 = (const float4*)sW;
    #pragma unroll 4
    for (int k = 0; k < 128; ++k) {
        float4 a = sA4[k * 16 + ty];
        float4 w0 = sW4[k * 32 + tx * 2 + 0];
        float4 w1 = sW4[k * 32 + tx * 2 + 1];
        float av[4] = {a.x, a.y, a.z, a.w};
        float wv[8] = {w0.x, w0.y, w0.z, w0.w, w1.x, w1.y, w1.z, w1.w};
        #pragma unroll
        for (int i = 0; i < 4; i++)
            #pragma unroll
            for (int j = 0; j < 8; j++) acc[i][j] += av[i] * wv[j];
    }
    #pragma unroll
    for (int i = 0; i < 4; i++) {
        float4* cp = (float4*)(C + (size_t)(m0 + ty * 4 + i) * DD + tx * 8);
        cp[0] = make_float4(acc[i][0], acc[i][1], acc[i][2], acc[i][3]);
        cp[1] = make_float4(acc[i][4], acc[i][5], acc[i][6], acc[i][7]);
    }
}

// ---------------- final: LN -> ReLU -> Wp2 -> tanh*0.1 -> new_xyz (f32) ---
__global__ void k_final(const float* __restrict__ Z, const float* __restrict__ bp1,
                        const float* __restrict__ lng, const float* __restrict__ lnb,
                        const float* __restrict__ Wp2, const float* __restrict__ bp2,
                        const float* __restrict__ xyz, float* __restrict__ out0) {
    int m = blockIdx.x * 4 + (threadIdx.x >> 6);
    int lane = threadIdx.x & 63;
    int b = m >> 12, n = m & 4095;
    const float2* zp = (const float2*)(Z + (size_t)m * DD);
    float2 z = zp[lane];
    float z0 = z.x + bp1[lane * 2];
    float z1 = z.y + bp1[lane * 2 + 1];
    float s = z0 + z1;
    #pragma unroll
    for (int o = 32; o; o >>= 1) s += __shfl_xor(s, o);
    float mu = s * (1.f / 128.f);
    float d0 = z0 - mu, d1 = z1 - mu;
    float v = d0 * d0 + d1 * d1;
    #pragma unroll
    for (int o = 32; o; o >>= 1) v += __shfl_xor(v, o);
    float rstd = rsqrtf(v * (1.f / 128.f) + 1e-5f);
    float r0 = d0 * rstd * lng[lane * 2] + lnb[lane * 2];
    float r1 = d1 * rstd * lng[lane * 2 + 1] + lnb[lane * 2 + 1];
    r0 = fmaxf(r0, 0.f); r1 = fmaxf(r1, 0.f);
    float off[6];
    #pragma unroll
    for (int o = 0; o < 6; o++) {
        float p = r0 * Wp2[(lane * 2) * 6 + o] + r1 * Wp2[(lane * 2 + 1) * 6 + o];
        #pragma unroll
        for (int x = 32; x; x >>= 1) p += __shfl_xor(p, x);
        off[o] = p;
    }
    if (lane == 0) {
        #pragma unroll
        for (int c = 0; c < 3; c++) {
            float base = xyz[((size_t)b * 3 + c) * NN + n];
            #pragma unroll
            for (int u = 0; u < 2; u++) {
                float val = tanhf(off[c * 2 + u] + bp2[c * 2 + u]) * 0.1f;
                out0[((size_t)b * 3 + c) * (2 * NN) + u * NN + n] = base + val;
            }
        }
    }
}

// ---------------- new_feat[b,k,n] = h[(b*N+n),k]  (f32) -------------------
__global__ void k_feat_out(const float* __restrict__ h, float* __restrict__ out1) {
    __shared__ float tile[64][65];
    int b = blockIdx.z, kp = blockIdx.y;
    int n0 = blockIdx.x * 64;
    int t = threadIdx.x;
    int lane = t & 63, grp = t >> 6;
    int k0 = kp * 64;
    for (int r = grp; r < 64; r += 4)
        tile[r][lane] = h[(size_t)(b * NN + n0 + r) * DD + k0 + lane];
    __syncthreads();
    for (int r = grp; r < 64; r += 4)
        out1[((size_t)(b * DD + k0 + r)) * NN + n0 + lane] = tile[lane][r];
}

extern "C" void kernel_launch(void* const* d_in, const int* in_sizes, int n_in,
                              void* d_out, int out_size, void* d_ws, size_t ws_size,
                              hipStream_t stream) {
    const float* xyz  = (const float*)d_in[0];
    const float* feat = (const float*)d_in[1];
    const float* Wa   = (const float*)d_in[2];
    const float* ba   = (const float*)d_in[3];
    const float* Wb   = (const float*)d_in[4];
    const float* bb   = (const float*)d_in[5];
    const float* Wp1  = (const float*)d_in[6];
    const float* bp1  = (const float*)d_in[7];
    const float* lng  = (const float*)d_in[8];
    const float* lnb  = (const float*)d_in[9];
    const float* Wp2  = (const float*)d_in[10];
    const float* bp2  = (const float*)d_in[11];

    float* h   = (float*)d_ws;                 // 8 MB
    float* X   = h + (size_t)MM * DD;          // 8 MB
    float* sq  = X + (size_t)MM * DD;          // 64 KB
    int*   idx = (int*)(sq + MM);              // 512 KB   (total 16.56 MB)

    float* out0 = (float*)d_out;                          // (B,3,2N)
    float* out1 = out0 + (size_t)BN * 3 * 2 * NN;         // (B,DIM,N)

    k_init_h<<<dim3(NN / 64, BN), 256, 0, stream>>>(feat, h);

    for (int i = 0; i < NBLK; i++) {
        k_sq<<<MM / 4, 256, 0, stream>>>(h, sq);
        k_knn<<<dim3(NN / 64, BN), 256, 0, stream>>>(h, sq, idx);
        k_gcn<<<MM / 64, 256, 0, stream>>>(h, idx, Wa + (size_t)i * DD * DD, ba + i * DD, X, 0);
        k_gcn<<<MM / 64, 256, 0, stream>>>(X, idx, Wb + (size_t)i * DD * DD, bb + i * DD, h, 1);
    }

    k_gemm<<<MM / 64, 256, 0, stream>>>(h, Wp1, X);
    k_final<<<MM / 4, 256, 0, stream>>>(X, bp1, lng, lnb, Wp2, bp2, xyz, out0);
    k_feat_out<<<dim3(NN / 64, 2, BN), 256, 0, stream>>>(h, out1);
}

// Round 11
// 5661.940 us; speedup vs baseline: 1.5215x; 1.3987x over previous
//
#include <hip/hip_runtime.h>
#include <math.h>

#define BN 4
#define NN 4096
#define MM 16384   // BN*NN
#define DD 128
#define KK 8
#define NBLK 12

// ---------------- init: h[(b*N+n), k] = feat[b, k, n] ----------------------
__global__ void k_init_h(const float* __restrict__ feat, float* __restrict__ h) {
    __shared__ float tile[64][65];
    int b = blockIdx.y;
    int n0 = blockIdx.x * 64;
    int t = threadIdx.x;
    int lane = t & 63, grp = t >> 6;
    for (int kp = 0; kp < 2; ++kp) {
        int k0 = kp * 64;
        for (int r = grp; r < 64; r += 4)
            tile[r][lane] = feat[((size_t)(b * DD + k0 + r)) * NN + n0 + lane];
        __syncthreads();
        for (int r = grp; r < 64; r += 4)
            h[(size_t)(b * NN + n0 + r) * DD + k0 + lane] = tile[lane][r];
        __syncthreads();
    }
}

// ---------------- sq[m] = sum_k h[m,k]^2 ----------------------------------
__global__ void k_sq(const float* __restrict__ h, float* __restrict__ sq) {
    int m = blockIdx.x * 4 + (threadIdx.x >> 6);
    int lane = threadIdx.x & 63;
    const float2* hp = (const float2*)(h + (size_t)m * DD);
    float2 v = hp[lane];
    float s = v.x * v.x + v.y * v.y;
    #pragma unroll
    for (int o = 32; o; o >>= 1) s += __shfl_xor(s, o);
    if (lane == 0) sq[m] = s;
}

// ---- inline-asm FMA: pins one IEEE fma per call, opaque to the optimizer --
__device__ __forceinline__ float fma_asm(float a, float b, float c) {
    float d;
    asm("v_fma_f32 %0, %1, %2, %3" : "=v"(d) : "v"(a), "v"(b), "v"(c));
    return d;
}

// ---------------- kNN v8: round-9 arithmetic, query-split for occupancy ---
// grid (NN/32, BN), block 256. 32 queries/block, full 4096-candidate scan.
// Thread (tx,ty) owns queries ty*2+{0,1} and candidates tx+16j per tile —
// per-(query,tx) partial lists are built by the identical insertion sequence
// as round 9 (c0 ascending, j=0..3), and the merge scan uses q&31 which is
// invariant under the 64->32 block-local reindexing, so idx is bit-identical
// in both value and order. LDS ~51KB -> 512 blocks = 2 blocks/CU.
__global__ __launch_bounds__(256) void k_knn(const float* __restrict__ h,
                                             const float* __restrict__ sq,
                                             int* __restrict__ idx) {
    __shared__ float sQ[32 * 132];
    __shared__ float sC[64 * 132];
    __shared__ float sSq[64];
    __shared__ float sQq[32];
    int b = blockIdx.y;
    int q0 = blockIdx.x * 32;
    int t = threadIdx.x;
    int tx = t & 15, ty = t >> 4;
    const float* hb = h + (size_t)b * NN * DD;

    float4* sQ4w = (float4*)sQ;
    float4* sC4w = (float4*)sC;
    const float4* sQ4 = (const float4*)sQ;
    const float4* sC4 = (const float4*)sC;

    // stage Q tile row-major (32 rows)
    {
        const float4* src = (const float4*)(hb + (size_t)q0 * DD);
        #pragma unroll
        for (int i2 = 0; i2 < 4; i2++) {
            int e = t + i2 * 256;
            int row = e >> 5, k4 = e & 31;
            sQ4w[row * 33 + k4] = src[row * 32 + k4];
        }
        if (t < 32) sQq[t] = sq[b * NN + q0 + t];
    }

    float d8[2][8];
    int   id8[2][8];
    float wv[2];
    int   wsl[2];
    #pragma unroll
    for (int i = 0; i < 2; i++) {
        wv[i] = 1e30f; wsl[i] = 0;
        #pragma unroll
        for (int s = 0; s < 8; s++) { d8[i][s] = 1e30f; id8[i][s] = 0; }
    }

    for (int c0 = 0; c0 < NN; c0 += 64) {
        __syncthreads();
        {
            const float4* src = (const float4*)(hb + (size_t)c0 * DD);
            #pragma unroll
            for (int i2 = 0; i2 < 8; i2++) {
                int e = t + i2 * 256;
                int row = e >> 5, k4 = e & 31;
                sC4w[row * 33 + k4] = src[row * 32 + k4];
            }
            if (t < 64) sSq[t] = sq[b * NN + c0 + t];
        }
        __syncthreads();

        float acc[2][4];
        #pragma unroll
        for (int i = 0; i < 2; i++)
            #pragma unroll
            for (int j = 0; j < 4; j++) acc[i][j] = 0.f;

        // asm-locked chains: acc[i][j] accumulates k=0..127 strictly ascending
        #pragma unroll 2
        for (int kq = 0; kq < 32; ++kq) {
            float4 qa[2], ca[4];
            #pragma unroll
            for (int i = 0; i < 2; i++) qa[i] = sQ4[(ty * 2 + i) * 33 + kq];
            #pragma unroll
            for (int j = 0; j < 4; j++) ca[j] = sC4[(tx + 16 * j) * 33 + kq];
            #pragma unroll
            for (int i = 0; i < 2; i++)
                #pragma unroll
                for (int j = 0; j < 4; j++) {
                    acc[i][j] = fma_asm(qa[i].x, ca[j].x, acc[i][j]);
                    acc[i][j] = fma_asm(qa[i].y, ca[j].y, acc[i][j]);
                    acc[i][j] = fma_asm(qa[i].z, ca[j].z, acc[i][j]);
                    acc[i][j] = fma_asm(qa[i].w, ca[j].w, acc[i][j]);
                }
        }

        // epilogue: same per-list insertion sequence as round 9
        #pragma unroll
        for (int j = 0; j < 4; j++) {
            int cl = c0 + tx + 16 * j;
            float sc = sSq[tx + 16 * j];
            #pragma unroll
            for (int i = 0; i < 2; i++) {
                int ql = q0 + ty * 2 + i;
                float key = (sQq[ty * 2 + i] + sc) - 2.f * acc[i][j];
                if (cl != ql && key < wv[i]) {
                    #pragma unroll
                    for (int s = 0; s < 8; s++)
                        if (s == wsl[i]) { d8[i][s] = key; id8[i][s] = cl; }
                    float w = d8[i][0]; int sl = 0;
                    #pragma unroll
                    for (int s = 1; s < 8; s++)
                        if (d8[i][s] > w) { w = d8[i][s]; sl = s; }
                    wv[i] = w; wsl[i] = sl;
                }
            }
        }
    }

    // merge 16 partial top-8s per query via LDS — round-9 scan order
    // (q&31 is invariant: (Q mod 64)&31 == (Q mod 32) == block-local q here)
    __syncthreads();
    int* sCi = (int*)sC;
    #pragma unroll
    for (int i = 0; i < 2; i++) {
        int q = ty * 2 + i;
        #pragma unroll
        for (int s = 0; s < 8; s++) {
            sQ[q * 128 + tx * 8 + s] = d8[i][s];
            sCi[q * 128 + tx * 8 + s] = id8[i][s];
        }
    }
    __syncthreads();
    if (t < 32) {
        int q = t;
        float bd[8]; int bi[8]; float w = 1e30f; int sl = 0;
        #pragma unroll
        for (int s = 0; s < 8; s++) { bd[s] = 1e30f; bi[s] = 0; }
        for (int e = 0; e < 128; ++e) {
            int e2 = (e & 96) | ((e & 31) ^ (q & 31));
            float key = sQ[q * 128 + e2];
            int cd = sCi[q * 128 + e2];
            if (key < w) {
                #pragma unroll
                for (int s = 0; s < 8; s++)
                    if (s == sl) { bd[s] = key; bi[s] = cd; }
                w = bd[0]; sl = 0;
                #pragma unroll
                for (int s = 1; s < 8; s++)
                    if (bd[s] > w) { w = bd[s]; sl = s; }
            }
        }
        int* op = idx + (size_t)(b * NN + q0 + q) * KK;
        #pragma unroll
        for (int s = 0; s < 8; s++) op[s] = b * NN + bi[s];
    }
}

// ------- fused GCN: agg-first + GEMM.  mode 0: R = relu(agg(S)@W + b)
//                                       mode 1: R = R + agg(S)@W + b
__global__ __launch_bounds__(256) void k_gcn(const float* __restrict__ S,
                                             const int* __restrict__ idx,
                                             const float* __restrict__ W,
                                             const float* __restrict__ bias,
                                             float* __restrict__ R,
                                             int mode) {
    __shared__ float sW[128 * 128];  // [k][n] 64KB
    __shared__ float sA[128 * 64];   // [k][m] 32KB
    int t = threadIdx.x;
    int m0 = blockIdx.x * 64;

    {
        int row = t >> 2, quad = t & 3;
        size_t gm = m0 + row;
        const float4* S4 = (const float4*)S;
        const int* ip = idx + gm * KK;
        int nb[8];
        #pragma unroll
        for (int j = 0; j < 8; j++) nb[j] = ip[j];
        float4 a[8];
        #pragma unroll
        for (int j = 0; j < 8; j++) a[j] = S4[gm * 32 + quad * 8 + j];
        for (int e = 0; e < 8; e++) {
            const float4* p = S4 + (size_t)nb[e] * 32 + quad * 8;
            #pragma unroll
            for (int j = 0; j < 8; j++) {
                float4 v = p[j];
                a[j].x += v.x; a[j].y += v.y; a[j].z += v.z; a[j].w += v.w;
            }
        }
        const float ninth = 1.f / 9.f;
        #pragma unroll
        for (int j = 0; j < 8; j++) {
            int k = quad * 32 + j * 4;
            sA[(k + 0) * 64 + row] = a[j].x * ninth;
            sA[(k + 1) * 64 + row] = a[j].y * ninth;
            sA[(k + 2) * 64 + row] = a[j].z * ninth;
            sA[(k + 3) * 64 + row] = a[j].w * ninth;
        }
    }
    {
        const float4* w4 = (const float4*)W;
        float4* sW4w = (float4*)sW;
        for (int e = t; e < 4096; e += 256) sW4w[e] = w4[e];
    }
    __syncthreads();

    int tx = t & 15, ty = t >> 4;
    float acc[4][8];
    #pragma unroll
    for (int i = 0; i < 4; i++)
        #pragma unroll
        for (int j = 0; j < 8; j++) acc[i][j] = 0.f;

    const float4* sA4 = (const float4*)sA;
    const float4* sW4 = (const float4*)sW;
    #pragma unroll 4
    for (int k = 0; k < 128; ++k) {
        float4 a = sA4[k * 16 + ty];
        float4 w0 = sW4[k * 32 + tx * 2 + 0];
        float4 w1 = sW4[k * 32 + tx * 2 + 1];
        float av[4] = {a.x, a.y, a.z, a.w};
        float wv[8] = {w0.x, w0.y, w0.z, w0.w, w1.x, w1.y, w1.z, w1.w};
        #pragma unroll
        for (int i = 0; i < 4; i++)
            #pragma unroll
            for (int j = 0; j < 8; j++) acc[i][j] += av[i] * wv[j];
    }

    float bia[8];
    #pragma unroll
    for (int j = 0; j < 8; j++) bia[j] = bias[tx * 8 + j];

    #pragma unroll
    for (int i = 0; i < 4; i++) {
        size_t m = m0 + ty * 4 + i;
        float4* rp = (float4*)(R + m * DD + tx * 8);
        float v[8];
        #pragma unroll
        for (int j = 0; j < 8; j++) v[j] = acc[i][j] + bia[j];
        if (mode == 0) {
            #pragma unroll
            for (int j = 0; j < 8; j++) v[j] = fmaxf(v[j], 0.f);
        } else {
            float4 r0 = rp[0], r1 = rp[1];
            v[0] += r0.x; v[1] += r0.y; v[2] += r0.z; v[3] += r0.w;
            v[4] += r1.x; v[5] += r1.y; v[6] += r1.z; v[7] += r1.w;
        }
        rp[0] = make_float4(v[0], v[1], v[2], v[3]);
        rp[1] = make_float4(v[4], v[5], v[6], v[7]);
    }
}

// ---------------- plain GEMM (final h @ Wp1) ------------------------------
__global__ __launch_bounds__(256) void k_gemm(const float* __restrict__ A,
                                              const float* __restrict__ W,
                                              float* __restrict__ C) {
    __shared__ float sW[128 * 128];
    __shared__ float sA[128 * 64];
    int t = threadIdx.x;
    int m0 = blockIdx.x * 64;

    const float4* w4 = (const float4*)W;
    float4* sW4w = (float4*)sW;
    for (int e = t; e < 4096; e += 256) sW4w[e] = w4[e];

    const float4* A4 = (const float4*)(A + (size_t)m0 * DD);
    for (int e = t; e < 64 * 32; e += 256) {
        int row = e >> 5, c4 = e & 31;
        float4 v = A4[row * 32 + c4];
        sA[(c4 * 4 + 0) * 64 + row] = v.x;
        sA[(c4 * 4 + 1) * 64 + row] = v.y;
        sA[(c4 * 4 + 2) * 64 + row] = v.z;
        sA[(c4 * 4 + 3) * 64 + row] = v.w;
    }
    __syncthreads();

    int tx = t & 15, ty = t >> 4;
    float acc[4][8];
    #pragma unroll
    for (int i = 0; i < 4; i++)
        #pragma unroll
        for (int j = 0; j < 8; j++) acc[i][j] = 0.f;

    const float4* sA4 = (const float4*)sA;
    const float4* sW4 = (const float4*)sW;
    #pragma unroll 4
    for (int k = 0; k < 128; ++k) {
        float4 a = sA4[k * 16 + ty];
        float4 w0 = sW4[k * 32 + tx * 2 + 0];
        float4 w1 = sW4[k * 32 + tx * 2 + 1];
        float av[4] = {a.x, a.y, a.z, a.w};
        float wv[8] = {w0.x, w0.y, w0.z, w0.w, w1.x, w1.y, w1.z, w1.w};
        #pragma unroll
        for (int i = 0; i < 4; i++)
            #pragma unroll
            for (int j = 0; j < 8; j++) acc[i][j] += av[i] * wv[j];
    }
    #pragma unroll
    for (int i = 0; i < 4; i++) {
        float4* cp = (float4*)(C + (size_t)(m0 + ty * 4 + i) * DD + tx * 8);
        cp[0] = make_float4(acc[i][0], acc[i][1], acc[i][2], acc[i][3]);
        cp[1] = make_float4(acc[i][4], acc[i][5], acc[i][6], acc[i][7]);
    }
}

// ---------------- final: LN -> ReLU -> Wp2 -> tanh*0.1 -> new_xyz (f32) ---
__global__ void k_final(const float* __restrict__ Z, const float* __restrict__ bp1,
                        const float* __restrict__ lng, const float* __restrict__ lnb,
                        const float* __restrict__ Wp2, const float* __restrict__ bp2,
                        const float* __restrict__ xyz, float* __restrict__ out0) {
    int m = blockIdx.x * 4 + (threadIdx.x >> 6);
    int lane = threadIdx.x & 63;
    int b = m >> 12, n = m & 4095;
    const float2* zp = (const float2*)(Z + (size_t)m * DD);
    float2 z = zp[lane];
    float z0 = z.x + bp1[lane * 2];
    float z1 = z.y + bp1[lane * 2 + 1];
    float s = z0 + z1;
    #pragma unroll
    for (int o = 32; o; o >>= 1) s += __shfl_xor(s, o);
    float mu = s * (1.f / 128.f);
    float d0 = z0 - mu, d1 = z1 - mu;
    float v = d0 * d0 + d1 * d1;
    #pragma unroll
    for (int o = 32; o; o >>= 1) v += __shfl_xor(v, o);
    float rstd = rsqrtf(v * (1.f / 128.f) + 1e-5f);
    float r0 = d0 * rstd * lng[lane * 2] + lnb[lane * 2];
    float r1 = d1 * rstd * lng[lane * 2 + 1] + lnb[lane * 2 + 1];
    r0 = fmaxf(r0, 0.f); r1 = fmaxf(r1, 0.f);
    float off[6];
    #pragma unroll
    for (int o = 0; o < 6; o++) {
        float p = r0 * Wp2[(lane * 2) * 6 + o] + r1 * Wp2[(lane * 2 + 1) * 6 + o];
        #pragma unroll
        for (int x = 32; x; x >>= 1) p += __shfl_xor(p, x);
        off[o] = p;
    }
    if (lane == 0) {
        #pragma unroll
        for (int c = 0; c < 3; c++) {
            float base = xyz[((size_t)b * 3 + c) * NN + n];
            #pragma unroll
            for (int u = 0; u < 2; u++) {
                float val = tanhf(off[c * 2 + u] + bp2[c * 2 + u]) * 0.1f;
                out0[((size_t)b * 3 + c) * (2 * NN) + u * NN + n] = base + val;
            }
        }
    }
}

// ---------------- new_feat[b,k,n] = h[(b*N+n),k]  (f32) -------------------
__global__ void k_feat_out(const float* __restrict__ h, float* __restrict__ out1) {
    __shared__ float tile[64][65];
    int b = blockIdx.z, kp = blockIdx.y;
    int n0 = blockIdx.x * 64;
    int t = threadIdx.x;
    int lane = t & 63, grp = t >> 6;
    int k0 = kp * 64;
    for (int r = grp; r < 64; r += 4)
        tile[r][lane] = h[(size_t)(b * NN + n0 + r) * DD + k0 + lane];
    __syncthreads();
    for (int r = grp; r < 64; r += 4)
        out1[((size_t)(b * DD + k0 + r)) * NN + n0 + lane] = tile[lane][r];
}

extern "C" void kernel_launch(void* const* d_in, const int* in_sizes, int n_in,
                              void* d_out, int out_size, void* d_ws, size_t ws_size,
                              hipStream_t stream) {
    const float* xyz  = (const float*)d_in[0];
    const float* feat = (const float*)d_in[1];
    const float* Wa   = (const float*)d_in[2];
    const float* ba   = (const float*)d_in[3];
    const float* Wb   = (const float*)d_in[4];
    const float* bb   = (const float*)d_in[5];
    const float* Wp1  = (const float*)d_in[6];
    const float* bp1  = (const float*)d_in[7];
    const float* lng  = (const float*)d_in[8];
    const float* lnb  = (const float*)d_in[9];
    const float* Wp2  = (const float*)d_in[10];
    const float* bp2  = (const float*)d_in[11];

    float* h   = (float*)d_ws;                 // 8 MB
    float* X   = h + (size_t)MM * DD;          // 8 MB
    float* sq  = X + (size_t)MM * DD;          // 64 KB
    int*   idx = (int*)(sq + MM);              // 512 KB   (total 16.56 MB)

    float* out0 = (float*)d_out;                          // (B,3,2N)
    float* out1 = out0 + (size_t)BN * 3 * 2 * NN;         // (B,DIM,N)

    k_init_h<<<dim3(NN / 64, BN), 256, 0, stream>>>(feat, h);

    for (int i = 0; i < NBLK; i++) {
        k_sq<<<MM / 4, 256, 0, stream>>>(h, sq);
        k_knn<<<dim3(NN / 32, BN), 256, 0, stream>>>(h, sq, idx);
        k_gcn<<<MM / 64, 256, 0, stream>>>(h, idx, Wa + (size_t)i * DD * DD, ba + i * DD, X, 0);
        k_gcn<<<MM / 64, 256, 0, stream>>>(X, idx, Wb + (size_t)i * DD * DD, bb + i * DD, h, 1);
    }

    k_gemm<<<MM / 64, 256, 0, stream>>>(h, Wp1, X);
    k_final<<<MM / 4, 256, 0, stream>>>(X, bp1, lng, lnb, Wp2, bp2, xyz, out0);
    k_feat_out<<<dim3(NN / 64, 2, BN), 256, 0, stream>>>(h, out1);
}